// Round 4
// baseline (257.168 us; speedup 1.0000x reference)
//
#include <hip/hip_runtime.h>
#include <hip/hip_fp16.h>

// GMM (MoNet) graph conv, 2 layers.
// R3 -> R4: GEMM commutes with the gather: h[n] = sum_k (sum_e g[e,k] x[col e]) W1[k].
// Gather RAW fp16 features (128 B/edge vs 192 B) into per-node aggregate s (fp32 regs),
// then apply W from LDS in the same kernel (xw_tiled kernels eliminated).
// Pipeline: prep (gauss4 + x->fp16) -> fused_conv<64,32> (h fp16) -> fused_conv<32,16> (out f32).

#define KK 3

__global__ void prep_kernel(const float* __restrict__ p, const float* __restrict__ mu,
                            const float* __restrict__ sigma, float4* __restrict__ gauss4,
                            const float* __restrict__ x, __half* __restrict__ xh,
                            int E, int NX8) {
    int i = blockIdx.x * blockDim.x + threadIdx.x;
    if (i < E) {
        float p0 = p[2 * i], p1 = p[2 * i + 1];
        float4 g;
        float* gp = (float*)&g;
#pragma unroll
        for (int k = 0; k < KK; ++k) {
            float m0 = mu[2 * k], m1 = mu[2 * k + 1];
            float s0 = sigma[2 * k], s1 = sigma[2 * k + 1];
            float d0 = p0 - m0, d1 = p1 - m1;
            float q = (d0 * d0) / (s0 * s0) + (d1 * d1) / (s1 * s1);
            gp[k] = __expf(-0.5f * q);
        }
        g.w = 0.f;
        gauss4[i] = g;
    }
    if (i < NX8) {   // cast 8 floats -> 8 halves per thread
        float4 v0 = ((const float4*)x)[2 * i];
        float4 v1 = ((const float4*)x)[2 * i + 1];
        union { __half h[8]; float4 v; } o;
        o.h[0] = __float2half(v0.x); o.h[1] = __float2half(v0.y);
        o.h[2] = __float2half(v0.z); o.h[3] = __float2half(v0.w);
        o.h[4] = __float2half(v1.x); o.h[5] = __float2half(v1.y);
        o.h[6] = __float2half(v1.z); o.h[7] = __float2half(v1.w);
        ((float4*)xh)[i] = o.v;
    }
}

// Block = 64 nodes. Phase 1: aggregate s[j=k*F+f][node] = sum_e g[e,k]*xh[col e][f]
// (lane covers feature; F=32 packs 2 nodes per wave pass; 16 gathers in flight).
// Phase 2: y[n, o] = sum_j s[j][n] * W[j][o]  (lane = node, wave covers H/4 outputs).
// sT pad 66 halves: write banks (f+ni)%32, read banks (j+(lane>>1))%32 -> conflict-free.
template <int F, int H, bool OUT_HALF>
__global__ __launch_bounds__(256) void fused_conv(
    const int* __restrict__ row_ptr, const int* __restrict__ col_idx,
    const float4* __restrict__ gauss4, const __half* __restrict__ xh,
    const float* __restrict__ W, void* __restrict__ yout, int N) {
    constexpr int J = KK * F;        // 192 or 96
    constexpr int NPP = 64 / F;      // nodes per wave pass: 1 or 2
    constexpr int OPW = H / 4;       // outputs per wave in phase 2: 8 or 4

    __shared__ __half sT[J * 66];
    __shared__ float wls[J * H];

    const int tid  = threadIdx.x;
    const int wv   = tid >> 6;
    const int lane = tid & 63;
    const int n0   = blockIdx.x * 64;

    // stage W ([k][f][h] flat == [j][h], contiguous)
    for (int i = tid; i < J * H / 4; i += 256)
        ((float4*)wls)[i] = ((const float4*)W)[i];

    const int f   = lane & (F - 1);
    const int sub = (F == 64) ? 0 : (lane >> 5);

    for (int it = 0; it < 16 / NPP; ++it) {
        const int ni = wv * 16 + it * NPP + sub;
        const int n  = n0 + ni;
        float a0 = 0.f, a1 = 0.f, a2 = 0.f;
        if (n < N) {
            int e0 = row_ptr[n], e1 = row_ptr[n + 1];
            int e = e0;
            for (; e + 16 <= e1; e += 16) {
                int cols[16];
#pragma unroll
                for (int j = 0; j < 16; ++j) cols[j] = col_idx[e + j];
                __half xr[16];
#pragma unroll
                for (int j = 0; j < 16; ++j) xr[j] = xh[(size_t)cols[j] * F + f];
#pragma unroll
                for (int j = 0; j < 16; ++j) {
                    float4 g = gauss4[e + j];
                    float xv = __half2float(xr[j]);
                    a0 = fmaf(g.x, xv, a0);
                    a1 = fmaf(g.y, xv, a1);
                    a2 = fmaf(g.z, xv, a2);
                }
            }
            for (; e < e1; ++e) {
                int c = col_idx[e];
                float4 g = gauss4[e];
                float xv = __half2float(xh[(size_t)c * F + f]);
                a0 = fmaf(g.x, xv, a0);
                a1 = fmaf(g.y, xv, a1);
                a2 = fmaf(g.z, xv, a2);
            }
        }
        sT[(0 * F + f) * 66 + ni] = __float2half(a0);
        sT[(1 * F + f) * 66 + ni] = __float2half(a1);
        sT[(2 * F + f) * 66 + ni] = __float2half(a2);
    }
    __syncthreads();

    // phase 2: lane = node, this wave computes outputs [wv*OPW, wv*OPW+OPW)
    {
        const int n = n0 + lane;
        float acc[OPW];
#pragma unroll
        for (int o = 0; o < OPW; ++o) acc[o] = 0.f;
        for (int j = 0; j < J; ++j) {
            float sv = __half2float(sT[j * 66 + lane]);
            const float4* wr = (const float4*)(wls + j * H + wv * OPW);
#pragma unroll
            for (int q = 0; q < OPW / 4; ++q) {
                float4 w = wr[q];
                acc[4 * q + 0] = fmaf(sv, w.x, acc[4 * q + 0]);
                acc[4 * q + 1] = fmaf(sv, w.y, acc[4 * q + 1]);
                acc[4 * q + 2] = fmaf(sv, w.z, acc[4 * q + 2]);
                acc[4 * q + 3] = fmaf(sv, w.w, acc[4 * q + 3]);
            }
        }
        if (n < N) {
            if constexpr (OUT_HALF) {
                union { __half h[8]; float4 v; } o;
#pragma unroll
                for (int q = 0; q < 8; ++q) o.h[q] = __float2half(acc[q]);
                *(float4*)((__half*)yout + (size_t)n * H + wv * OPW) = o.v;
            } else {
                float4 o = {acc[0], acc[1], acc[2], acc[3]};
                *(float4*)((float*)yout + (size_t)n * H + wv * OPW) = o;
            }
        }
    }
}

extern "C" void kernel_launch(void* const* d_in, const int* in_sizes, int n_in,
                              void* d_out, int out_size, void* d_ws, size_t ws_size,
                              hipStream_t stream) {
    const int* row_ptr  = (const int*)d_in[0];
    const int* col_idx  = (const int*)d_in[1];
    const float* x      = (const float*)d_in[2];
    const float* p      = (const float*)d_in[3];
    const float* mu     = (const float*)d_in[4];
    const float* sigma  = (const float*)d_in[5];
    const float* W1     = (const float*)d_in[6];
    const float* W2     = (const float*)d_in[7];

    const int N = in_sizes[0] - 1;
    const int E = in_sizes[1];

    float4* gauss4 = (float4*)d_ws;                       // E float4s
    __half* xh     = (__half*)(gauss4 + (size_t)E);       // N*64 fp16
    __half* hh     = xh + (size_t)N * 64;                 // N*32 fp16
    float*  out    = (float*)d_out;                       // N*16 f32

    const int B = 256;
    const int NX8 = N * 8;
    const int prep_n = (E > NX8 ? E : NX8);

    prep_kernel<<<(prep_n + B - 1) / B, B, 0, stream>>>(p, mu, sigma, gauss4, x, xh, E, NX8);

    const int nblocks = (N + 63) / 64;
    fused_conv<64, 32, true><<<nblocks, B, 0, stream>>>(row_ptr, col_idx, gauss4, xh, W1, (void*)hh, N);
    fused_conv<32, 16, false><<<nblocks, B, 0, stream>>>(row_ptr, col_idx, gauss4, hh, W2, (void*)out, N);
}